// Round 22
// baseline (271.089 us; speedup 1.0000x reference)
//
#include <hip/hip_runtime.h>
#include <hip/hip_bf16.h>

typedef unsigned short u16;
typedef unsigned int   u32;

using f32x4  = __attribute__((ext_vector_type(4)))  float;
using f32x16 = __attribute__((ext_vector_type(16))) float;
using s16x8  = __attribute__((ext_vector_type(8)))  short;
using b16x8  = __attribute__((ext_vector_type(8)))  __bf16;
using u32x4  = __attribute__((ext_vector_type(4)))  u32;

#define LOG2E 1.44269504088896f
#define QSC   (0.03125f * LOG2E)   // SCALE * log2(e), folded into q

__device__ __forceinline__ f32x4 mfma16(s16x8 a, s16x8 b, f32x4 c) {
  return __builtin_amdgcn_mfma_f32_16x16x32_bf16(
      __builtin_bit_cast(b16x8, a), __builtin_bit_cast(b16x8, b), c, 0, 0, 0);
}
__device__ __forceinline__ f32x16 mfma32(s16x8 a, s16x8 b, f32x16 c) {
  return __builtin_amdgcn_mfma_f32_32x32x16_bf16(
      __builtin_bit_cast(b16x8, a), __builtin_bit_cast(b16x8, b), c, 0, 0, 0);
}

__device__ __forceinline__ u16 f2bf(float f) {
  u32 u = __builtin_bit_cast(u32, f);
  u = (u + 0x7FFFu + ((u >> 16) & 1u)) >> 16;
  return (u16)u;
}
__device__ __forceinline__ float exp2_hw(float x) {
  float r;
  asm("v_exp_f32 %0, %1" : "=v"(r) : "v"(x));
  return r;
}
__device__ __forceinline__ u32 cvtpk(float a, float b) {   // (lo=a, hi=b) bf16 pair, RNE
  u32 r;
  asm("v_cvt_pk_bf16_f32 %0, %1, %2" : "=v"(r) : "v"(a), "v"(b));
  return r;
}

// async global->LDS, 16B per lane; LDS dest = wave-uniform base + lane*16
__device__ __forceinline__ void gload16(const void* g, void* l) {
  __builtin_amdgcn_global_load_lds(
      (const __attribute__((address_space(1))) u32*)g,
      (__attribute__((address_space(3))) u32*)l, 16, 0, 0);
}

// ---------------- prep: cvt3 + bias_rearrange fused (grid-range split) ------
__global__ void prep(const float* __restrict__ x, const float* __restrict__ wqkv,
                     const float* __restrict__ wproj, u16* __restrict__ outc,
                     const float* __restrict__ ab, u16* __restrict__ biasr) {
  __shared__ u16 T[32][72];
  if (blockIdx.x < 2048) {
    int i = blockIdx.x * 256 + threadIdx.x;
    const int stride = 2048 * 256;
    for (; i < 3145728; i += stride) {        // float4 groups, 12.6M elems total
      const float* src = (i < 2097152) ? x + 4 * (long)i
                       : (i < 2883584) ? wqkv + 4 * ((long)i - 2097152)
                                       : wproj + 4 * ((long)i - 2883584);
      const float4 v = *(const float4*)src;
      ushort4 o;
      o.x = f2bf(v.x); o.y = f2bf(v.y); o.z = f2bf(v.z); o.w = f2bf(v.w);
      ((ushort4*)outc)[i] = o;
    }
  } else {
    const int blk  = blockIdx.x - 2048;   // 0..2047
    const int tid  = threadIdx.x;
    const int slot = blk >> 5;            // 0..63
    const int kt   = blk & 31;            // 0..31
    {
      const int qr = tid >> 3;            // 0..31
      const int fc = (tid & 7) * 8;       // 0..56
      const float* src = ab + (long)(slot * 32 + qr) * 2048 + kt * 64 + fc;
      const float4 a = *(const float4*)(src);
      const float4 b = *(const float4*)(src + 4);
      u16 t[8];
      t[0] = f2bf(a.x * LOG2E); t[1] = f2bf(a.y * LOG2E);
      t[2] = f2bf(a.z * LOG2E); t[3] = f2bf(a.w * LOG2E);
      t[4] = f2bf(b.x * LOG2E); t[5] = f2bf(b.y * LOG2E);
      t[6] = f2bf(b.z * LOG2E); t[7] = f2bf(b.w * LOG2E);
      *(s16x8*)&T[qr][fc] = *(s16x8*)t;
    }
    __syncthreads();
    {
      const int chunk = tid >> 6;         // 0..3
      const int lane  = tid & 63;
      const int q5    = lane & 31;
      const int hi    = lane >> 5;
      u16 o[8];
#pragma unroll
      for (int e = 0; e < 8; ++e) {
        const int vidx = chunk * 8 + e;
        const int kb = vidx >> 4, r = vidx & 15;
        const int key = kb * 32 + (r & 3) + 8 * (r >> 2) + 4 * hi;
        o[e] = T[q5][key];
      }
      *(s16x8*)(biasr + ((long)blk * 256 + tid) * 8) = *(s16x8*)o;
    }
  }
}

// ---------------- QKV GEMM: 256x256 tile, BK=64, 8-phase counted-vmcnt ------
// C[8192,3072] = A[8192,1024] @ B[3072,1024]^T, bf16, qkv scatter epilogue.
// 512 thr = 8 waves (2Mx4N); per-wave out 128x64; acc[8][4] f32x4.
// LDS (dynamic, 128KB): A[2][256*64] @0/16384, B[2][256*64] @32768/49152.
// Even tiles -> buf0, odd -> buf1 (static).  8 phases per iteration process
// tiles 2i (ph1-4) and 2i+1 (ph5-8); each phase: ds_read quadrant frags,
// issue stage calls, 16 MFMA, barrier.  Quadrants in REVERSE row order
// (m=6,7 first) so each 64-row stage region was fully read >=1 barrier
// before being overwritten.  B-frags (8) front-loaded per K-tile, held in
// regs.  Stage ledger (2 gload16 calls per 64-row region):
//   ph1: B(2i+1)c2,c3 + A(2i+1)c0,c2   (tail of odd tile -> buf1)
//   ph3: A(2i+2)c1,c3   ph4: B(2i+2)c0,c1
//   ph5: B(2i+2)c2,c3   ph6: A(2i+2)c0,c2   (even tile -> buf0)
//   ph7: A(2i+3)c1,c3   ph8: B(2i+3)c0,c1   (head of next odd -> buf1)
// vmcnt(4) before ph4/ph8 barriers confirms exactly the tile needed next
// (steady outstanding after wait = 4; i=7 tail uses vmcnt(0)).  Safety of
// each stage vs reads verified region-by-region (see derivation r22).
__global__ __launch_bounds__(512)
void gemm_qkv(const u16* __restrict__ A, const u16* __restrict__ Bm,
              const float* __restrict__ bias0, const float* __restrict__ bias1,
              u16* __restrict__ oq, u16* __restrict__ ok, u16* __restrict__ ov)
{
  extern __shared__ u16 lds[];
  u16* const Al0 = lds;
  u16* const Al1 = lds + 16384;
  u16* const Bl0 = lds + 32768;
  u16* const Bl1 = lds + 49152;

  const int tid  = threadIdx.x;
  const int w    = tid >> 6;
  const int lane = tid & 63;
  const int lr   = lane & 15;
  const int lg   = lane >> 4;
  const int wr   = w >> 2, wc = w & 3;

  // XCD swizzle: 384 blocks = 8 * 48; each XCD gets 4 bm rows x 12 bn
  const int bid = blockIdx.x;
  const int swz = (bid & 7) * 48 + (bid >> 3);
  const int bn  = swz % 12, bm = swz / 12;

  const int srow = tid >> 3;            // 0..63
  const int skc  = (tid & 7) * 8;
  const u16* gA = A  + (long)(bm * 256 + srow) * 1024 + skc;
  const u16* gB = Bm + (long)(bn * 256 + srow) * 1024 + skc;

#define SA(DST, T, C) gload16(gA + (long)(C) * 65536 + (T) * 64, (DST) + (C) * 4096 + w * 512)
#define SB(DST, T, C) gload16(gB + (long)(C) * 65536 + (T) * 64, (DST) + (C) * 4096 + w * 512)

  f32x4 acc[8][4];
#pragma unroll
  for (int m = 0; m < 8; ++m)
#pragma unroll
    for (int n = 0; n < 4; ++n) acc[m][n] = (f32x4){0.f, 0.f, 0.f, 0.f};

  // prologue: tile0 (8 calls) + tile1 head (4 calls); confirm tile0
  SA(Al0, 0, 0); SA(Al0, 0, 1); SA(Al0, 0, 2); SA(Al0, 0, 3);
  SB(Bl0, 0, 0); SB(Bl0, 0, 1); SB(Bl0, 0, 2); SB(Bl0, 0, 3);
  SA(Al1, 1, 1); SA(Al1, 1, 3); SB(Bl1, 1, 0); SB(Bl1, 1, 1);
  asm volatile("s_waitcnt vmcnt(4)" ::: "memory");
  __syncthreads();

  const int abase = wr * 128;
  const int bbase = wc * 64;

// one phase: read A-frags for m=MB,MB+1 from ALD, issue STG, 16 MFMA, barrier
#define PHASE(ALD, MB, STG)                                                     \
  {                                                                             \
    const u16* ap0 = (ALD) + (abase + (MB) * 16 + lr) * 64 + lg * 8;            \
    const u16* ap1 = (ALD) + (abase + (MB) * 16 + 16 + lr) * 64 + lg * 8;       \
    const s16x8 a00 = *(const s16x8*)(ap0);                                     \
    const s16x8 a01 = *(const s16x8*)(ap0 + 32);                                \
    const s16x8 a10 = *(const s16x8*)(ap1);                                     \
    const s16x8 a11 = *(const s16x8*)(ap1 + 32);                                \
    STG;                                                                        \
    _Pragma("unroll")                                                           \
    for (int n = 0; n < 4; ++n) {                                               \
      acc[MB][n]     = mfma16(a00, bf[n][0], acc[MB][n]);                       \
      acc[MB][n]     = mfma16(a01, bf[n][1], acc[MB][n]);                       \
      acc[MB + 1][n] = mfma16(a10, bf[n][0], acc[MB + 1][n]);                   \
      acc[MB + 1][n] = mfma16(a11, bf[n][1], acc[MB + 1][n]);                   \
    }                                                                           \
  }

  for (int i = 0; i < 8; ++i) {
    const int t1 = 2 * i + 1, t2 = 2 * i + 2, t3 = 2 * i + 3;
    s16x8 bf[4][2];

    // ===== tile 2i from buf0 (phases 1-4) =====
#pragma unroll
    for (int n = 0; n < 4; ++n) {
      const u16* bp = Bl0 + (bbase + n * 16 + lr) * 64 + lg * 8;
      bf[n][0] = *(const s16x8*)(bp);
      bf[n][1] = *(const s16x8*)(bp + 32);
    }
    PHASE(Al0, 6, { SB(Bl1, t1, 2); SB(Bl1, t1, 3); SA(Al1, t1, 0); SA(Al1, t1, 2); });
    __syncthreads();
    PHASE(Al0, 4, {});
    __syncthreads();
    PHASE(Al0, 2, { if (t2 < 16) { SA(Al0, t2, 1); SA(Al0, t2, 3); } });
    __syncthreads();
    PHASE(Al0, 0, { if (t2 < 16) { SB(Bl0, t2, 0); SB(Bl0, t2, 1); } });
    if (i < 7) asm volatile("s_waitcnt vmcnt(4)" ::: "memory");
    else       asm volatile("s_waitcnt vmcnt(0)" ::: "memory");
    __syncthreads();

    // ===== tile 2i+1 from buf1 (phases 5-8) =====
#pragma unroll
    for (int n = 0; n < 4; ++n) {
      const u16* bp = Bl1 + (bbase + n * 16 + lr) * 64 + lg * 8;
      bf[n][0] = *(const s16x8*)(bp);
      bf[n][1] = *(const s16x8*)(bp + 32);
    }
    PHASE(Al1, 6, { if (t2 < 16) { SB(Bl0, t2, 2); SB(Bl0, t2, 3); } });
    __syncthreads();
    PHASE(Al1, 4, { if (t2 < 16) { SA(Al0, t2, 0); SA(Al0, t2, 2); } });
    __syncthreads();
    PHASE(Al1, 2, { if (t3 < 16) { SA(Al1, t3, 1); SA(Al1, t3, 3); } });
    __syncthreads();
    PHASE(Al1, 0, { if (t3 < 16) { SB(Bl1, t3, 0); SB(Bl1, t3, 1); } });
    if (i < 7) asm volatile("s_waitcnt vmcnt(4)" ::: "memory");
    else       asm volatile("s_waitcnt vmcnt(0)" ::: "memory");
    __syncthreads();
  }
#undef PHASE
#undef SA
#undef SB

  // epilogue: qkv scatter (same per-element mapping as the proven 128 kernel)
  const int gm0 = bm * 256 + wr * 128;
  const int gn0 = bn * 256 + wc * 64;
#pragma unroll
  for (int m = 0; m < 8; ++m) {
#pragma unroll
    for (int n = 0; n < 4; ++n) {
      const int col  = gn0 + n * 16 + lr;
      const int row0 = gm0 + m * 16 + lg * 4;
      const int which = col >> 10;          // 0=q 1=k 2=v
      const int cj    = col & 1023;
      const float badd = (which == 0) ? bias0[cj] : (which == 2 ? bias1[cj] : 0.f);
      const int h = cj >> 6, d = cj & 63;
#pragma unroll
      for (int r = 0; r < 4; ++r) {
        const int rowg = row0 + r;           // = b*2048 + l
        const int b = rowg >> 11, l = rowg & 2047;
        const int bh = b * 16 + h;
        float val = acc[m][n][r] + badd;
        if (which == 0) val *= QSC;          // fold softmax scale+log2e into q
        const u16 o = f2bf(val);
        if (which == 0)      oq[(bh * 2048 + l) * 64 + d] = o;
        else if (which == 1) ok[(bh * 2048 + l) * 64 + d] = o;
        else {
          // permute key bits 2<->3 so flash PV B-frags are lane-local
          const int lp = (l & ~12) | ((l & 4) << 1) | ((l & 8) >> 1);
          ov[(bh * 64 + d) * 2048 + lp] = o;
        }
      }
    }
  }
}

// ---------------- GEMM: C[M,N] = A[M,K] @ B[N,K]^T  (proj; r17-proven) ------
template<int EPI>
__global__ __launch_bounds__(256)
void gemm_bt(const u16* __restrict__ A, const u16* __restrict__ Bm,
             int M, int N, int K,
             const float* __restrict__ bias0,
             float* __restrict__ outf)
{
  __shared__ u16 As[2][128 * 32];
  __shared__ u16 Bs[2][128 * 32];

  const int tid  = threadIdx.x;
  const int w    = tid >> 6;
  const int lane = tid & 63;
  const int lr   = lane & 15;
  const int lg   = lane >> 4;
  const int wr   = w >> 1, wc = w & 1;

  const int bm = blockIdx.y, bn = blockIdx.x;

  f32x4 acc[4][4];
#pragma unroll
  for (int i = 0; i < 4; ++i)
#pragma unroll
    for (int j = 0; j < 4; ++j) acc[i][j] = (f32x4){0.f, 0.f, 0.f, 0.f};

  const int rowA = bm * 128 + (tid >> 2);
  const int rowB = bn * 128 + (tid >> 2);
  const int colk = (tid & 3) * 8;

  const u16* ga0 = A  + (long)rowA * K + colk;
  const u16* gb0 = Bm + (long)rowB * K + colk;

  gload16(ga0,          &As[0][w * 512]);
  gload16(ga0 + 64 * K, &As[0][2048 + w * 512]);
  gload16(gb0,          &Bs[0][w * 512]);
  gload16(gb0 + 64 * K, &Bs[0][2048 + w * 512]);
  asm volatile("s_waitcnt vmcnt(0)" ::: "memory");
  __syncthreads();

  const int NT = K >> 5;
  for (int t = 0; t < NT; ++t) {
    const int cur = t & 1;
    if (t + 1 < NT) {
      const u16* ga = ga0 + (t + 1) * 32;
      const u16* gb = gb0 + (t + 1) * 32;
      gload16(ga,          &As[cur ^ 1][w * 512]);
      gload16(ga + 64 * K, &As[cur ^ 1][2048 + w * 512]);
      gload16(gb,          &Bs[cur ^ 1][w * 512]);
      gload16(gb + 64 * K, &Bs[cur ^ 1][2048 + w * 512]);
    }

    s16x8 af[4], bfr[4];
#pragma unroll
    for (int mi = 0; mi < 4; ++mi)
      af[mi] = *(const s16x8*)(&As[cur][(wr * 64 + mi * 16 + lr) * 32 + lg * 8]);
#pragma unroll
    for (int ni = 0; ni < 4; ++ni)
      bfr[ni] = *(const s16x8*)(&Bs[cur][(wc * 64 + ni * 16 + lr) * 32 + lg * 8]);
#pragma unroll
    for (int mi = 0; mi < 4; ++mi)
#pragma unroll
      for (int ni = 0; ni < 4; ++ni)
        acc[mi][ni] = mfma16(af[mi], bfr[ni], acc[mi][ni]);

    asm volatile("s_waitcnt vmcnt(0)" ::: "memory");
    __syncthreads();
  }

  const int gm0 = bm * 128 + wr * 64;
  const int gn0 = bn * 128 + wc * 64;

#pragma unroll
  for (int mi = 0; mi < 4; ++mi) {
#pragma unroll
    for (int ni = 0; ni < 4; ++ni) {
      const int col  = gn0 + ni * 16 + lr;
      const int row0 = gm0 + mi * 16 + lg * 4;
      const float badd = bias0[col];
#pragma unroll
      for (int r = 0; r < 4; ++r)
        outf[(long)(row0 + r) * N + col] = acc[mi][ni][r] + badd;
    }
  }
}

// ---------------- flash attention ----------------
// r15/r17 structure VERBATIM (passed, 107.5us, VGPR 88).
// CONDEMNED (do not re-add): f32-bias scratch (r19/r20 absmax fails),
// s_setprio (r16: VGPR 88->128, -13%), __launch_bounds__ min-waves arg
// (r8/r9/r11 miscompiles).
__global__ __launch_bounds__(256)
void flash_attn(const u16* __restrict__ qbuf, const u16* __restrict__ kbuf,
                const u16* __restrict__ vtbuf, const u16* __restrict__ biasr,
                u16* __restrict__ oup)
{
  __shared__ u16 Ks[2][64 * 72];
  __shared__ u16 Vs[2][64 * 72];

  const int tid  = threadIdx.x;
  const int w    = tid >> 6;
  const int lane = tid & 63;
  const int lq   = lane & 31;
  const int hi   = lane >> 5;

  const int bid = blockIdx.x;
  const int swz = (bid & 7) * 128 + (bid >> 3);   // bijective, 1024 % 8 == 0
  const int bh  = swz >> 4, qt2 = swz & 15;
  const long base = (long)bh * (2048 * 64);

  const int qrow = qt2 * 128 + w * 32 + lq;
  s16x8 qf[4];
  {
    const u16* qp = qbuf + base + qrow * 64 + 8 * hi;
#pragma unroll
    for (int s = 0; s < 4; ++s) qf[s] = *(const s16x8*)(qp + 16 * s);
  }

  f32x16 oacc0, oacc1;
  float lacc[8];
#pragma unroll
  for (int r = 0; r < 16; ++r) { oacc0[r] = 0.f; oacc1[r] = 0.f; }
#pragma unroll
  for (int r = 0; r < 8; ++r) lacc[r] = 0.f;

  const u16* bslice = biasr + (long)(qt2 * 4 + w) * 65536 + lane * 8;

  const int sr  = tid >> 3;
  const int scc = tid & 7;
  const u16* kg = kbuf  + base + sr * 64   + scc * 8;
  const u16* vg = vtbuf + base + sr * 2048 + scc * 8;
  const int wo0 = sr * 72 + scc * 8;
  const int wo1 = (32 + sr) * 72 + scc * 8;

  {
    const s16x8 a0 = *(const s16x8*)(kg);
    const s16x8 a1 = *(const s16x8*)(kg + 2048);
    const s16x8 b0 = *(const s16x8*)(vg);
    const s16x8 b1 = *(const s16x8*)(vg + 65536);
    *(s16x8*)(&Ks[0][wo0]) = a0;  *(s16x8*)(&Ks[0][wo1]) = a1;
    *(s16x8*)(&Vs[0][wo0]) = b0;  *(s16x8*)(&Vs[0][wo1]) = b1;
  }
  __syncthreads();

  for (int kt = 0; kt < 32; ++kt) {
    const int cur = kt & 1;

    s16x8 nk0, nk1, nv0, nv1;
    if (kt < 31) {
      const u16* kn = kg + (kt + 1) * 4096;
      const u16* vn = vg + (kt + 1) * 64;
      nk0 = *(const s16x8*)(kn);
      nk1 = *(const s16x8*)(kn + 2048);
      nv0 = *(const s16x8*)(vn);
      nv1 = *(const s16x8*)(vn + 65536);
    }

    s16x8 kf0[4], kf1[4], vf0[4], vf1[4];
    {
      const u16* kb0 = &Ks[cur][lq * 72];
      const u16* kb1 = &Ks[cur][(32 + lq) * 72];
      const u16* vb0 = &Vs[cur][lq * 72];
      const u16* vb1 = &Vs[cur][(32 + lq) * 72];
#pragma unroll
      for (int s = 0; s < 4; ++s) {
        const int off = (2 * s + hi) * 8;
        kf0[s] = *(const s16x8*)(kb0 + off);
        kf1[s] = *(const s16x8*)(kb1 + off);
        vf0[s] = *(const s16x8*)(vb0 + off);
        vf1[s] = *(const s16x8*)(vb1 + off);
      }
    }

    u32x4 bb[4];
#pragma unroll
    for (int k = 0; k < 4; ++k)
      bb[k] = *(const u32x4*)(bslice + kt * 2048 + k * 512);

    f32x16 sa0, sa1;
#pragma unroll
    for (int jw = 0; jw < 8; ++jw) {
      const u32 w0 = bb[jw >> 2][jw & 3];
      const u32 w1 = bb[2 + (jw >> 2)][jw & 3];
      sa0[2 * jw]     = __builtin_bit_cast(float, w0 << 16);
      sa0[2 * jw + 1] = __builtin_bit_cast(float, w0 & 0xFFFF0000u);
      sa1[2 * jw]     = __builtin_bit_cast(float, w1 << 16);
      sa1[2 * jw + 1] = __builtin_bit_cast(float, w1 & 0xFFFF0000u);
    }

#pragma unroll
    for (int s = 0; s < 4; ++s) sa0 = mfma32(kf0[s], qf[s], sa0);
#pragma unroll
    for (int s = 0; s < 4; ++s) sa1 = mfma32(kf1[s], qf[s], sa1);

#pragma unroll
    for (int r = 0; r < 16; ++r) {
      sa0[r] = exp2_hw(sa0[r]);
      sa1[r] = exp2_hw(sa1[r]);
    }
#pragma unroll
    for (int r = 0; r < 8; ++r)
      lacc[r] += (sa0[r] + sa0[r + 8]) + (sa1[r] + sa1[r + 8]);

    s16x8 pf[4];
#pragma unroll
    for (int ks = 0; ks < 4; ++ks) {
      const f32x16 ps = (ks & 2) ? sa1 : sa0;
      const int o = (ks & 1) * 8;
      u32x4 tt;
      tt[0] = cvtpk(ps[o + 0], ps[o + 1]);
      tt[1] = cvtpk(ps[o + 2], ps[o + 3]);
      tt[2] = cvtpk(ps[o + 4], ps[o + 5]);
      tt[3] = cvtpk(ps[o + 6], ps[o + 7]);
      pf[ks] = __builtin_bit_cast(s16x8, tt);
    }

#pragma unroll
    for (int ks = 0; ks < 4; ++ks) {
      oacc0 = mfma32(vf0[ks], pf[ks], oacc0);
      oacc1 = mfma32(vf1[ks], pf[ks], oacc1);
    }

    if (kt < 31) {
      *(s16x8*)(&Ks[cur ^ 1][wo0]) = nk0;
      *(s16x8*)(&Ks[cur ^ 1][wo1]) = nk1;
      *(s16x8*)(&Vs[cur ^ 1][wo0]) = nv0;
      *(s16x8*)(&Vs[cur ^ 1][wo1]) = nv1;
    }
    __syncthreads();
  }

  u32 (*Os)[32][33] = (u32(*)[32][33])&Ks[0][0];
  const int b = bh >> 4, h = bh & 15;
  float l = ((lacc[0] + lacc[1]) + (lacc[2] + lacc[3]))
          + ((lacc[4] + lacc[5]) + (lacc[6] + lacc[7]));
  l += __shfl_xor(l, 32, 64);
  const float inv = 1.f / l;
#pragma unroll
  for (int i = 0; i < 8; ++i) {
    const int idx = (i & 1) + 2 * hi + 4 * (i >> 1);   // d0 = 2*idx
    Os[w][lq][idx]      = cvtpk(oacc0[2 * i] * inv, oacc0[2 * i + 1] * inv);
    Os[w][lq][idx + 16] = cvtpk(oacc1[2 * i] * inv, oacc1[2 * i + 1] * inv);
  }
  __syncthreads();
#pragma unroll
  for (int it = 0; it < 4; ++it) {
    const int q = it * 8 + (lane >> 3);
    const int c = (lane & 7) * 4;
    u32x4 v;
#pragma unroll
    for (int j = 0; j < 4; ++j) v[j] = Os[w][q][c + j];
    const long row = (long)(b * 2048 + qt2 * 128 + w * 32 + q);
    *(u32x4*)(oup + row * 1024 + h * 64 + (lane & 7) * 8) = v;
  }
}

extern "C" void kernel_launch(void* const* d_in, const int* in_sizes, int n_in,
                              void* d_out, int out_size, void* d_ws, size_t ws_size,
                              hipStream_t stream) {
  const float* x     = (const float*)d_in[0];
  const float* ab    = (const float*)d_in[1];
  const float* wqkv  = (const float*)d_in[2];
  const float* qbias = (const float*)d_in[3];
  const float* vbias = (const float*)d_in[4];
  const float* wproj = (const float*)d_in[5];
  const float* bproj = (const float*)d_in[6];
  float* out = (float*)d_out;

  char* ws = (char*)d_ws;
  if (ws_size < 83886080u) return;  // refuse to corrupt memory
  u16* xb     = (u16*)(ws);              // 16 MB; reused as oup after QKV GEMM
  u16* wqkvb  = (u16*)(ws + 16777216);   // 6 MB (contiguous with xb)
  u16* wprojb = (u16*)(ws + 23068672);   // 2 MB (contiguous with wqkvb)
  u16* biasr  = (u16*)(ws + 25165824);   // 8 MB  (attn_bias, fragment order)
  u16* qbuf   = (u16*)(ws + 33554432);   // 16 MB  [B,H,L,D] (q pre-scaled)
  u16* kbuf   = (u16*)(ws + 50331648);   // 16 MB  [B,H,L,D]
  u16* vtbuf  = (u16*)(ws + 67108864);   // 16 MB  [B,H,D,L'] (key-permuted)

  prep<<<dim3(4096), dim3(256), 0, stream>>>(x, wqkv, wproj, xb, ab, biasr);

  gemm_qkv<<<dim3(384), dim3(512), 131072, stream>>>(
      xb, wqkvb, qbias, vbias, qbuf, kbuf, vtbuf);

  flash_attn<<<dim3(1024), dim3(256), 0, stream>>>(qbuf, kbuf, vtbuf, biasr, xb);

  gemm_bt<1><<<dim3(8, 64), dim3(256), 0, stream>>>(
      xb, wprojb, 8192, 1024, 1024, bproj, out);
}

// Round 23
// 227.918 us; speedup vs baseline: 1.1894x; 1.1894x over previous
//
#include <hip/hip_runtime.h>
#include <hip/hip_bf16.h>

typedef unsigned short u16;
typedef unsigned int   u32;

using f32x4  = __attribute__((ext_vector_type(4)))  float;
using f32x16 = __attribute__((ext_vector_type(16))) float;
using s16x8  = __attribute__((ext_vector_type(8)))  short;
using b16x8  = __attribute__((ext_vector_type(8)))  __bf16;
using u32x4  = __attribute__((ext_vector_type(4)))  u32;

#define LOG2E 1.44269504088896f
#define QSC   (0.03125f * LOG2E)   // SCALE * log2(e), folded into q

__device__ __forceinline__ f32x4 mfma16(s16x8 a, s16x8 b, f32x4 c) {
  return __builtin_amdgcn_mfma_f32_16x16x32_bf16(
      __builtin_bit_cast(b16x8, a), __builtin_bit_cast(b16x8, b), c, 0, 0, 0);
}
__device__ __forceinline__ f32x16 mfma32(s16x8 a, s16x8 b, f32x16 c) {
  return __builtin_amdgcn_mfma_f32_32x32x16_bf16(
      __builtin_bit_cast(b16x8, a), __builtin_bit_cast(b16x8, b), c, 0, 0, 0);
}

__device__ __forceinline__ u16 f2bf(float f) {
  u32 u = __builtin_bit_cast(u32, f);
  u = (u + 0x7FFFu + ((u >> 16) & 1u)) >> 16;
  return (u16)u;
}
__device__ __forceinline__ float exp2_hw(float x) {
  float r;
  asm("v_exp_f32 %0, %1" : "=v"(r) : "v"(x));
  return r;
}
__device__ __forceinline__ u32 cvtpk(float a, float b) {   // (lo=a, hi=b) bf16 pair, RNE
  u32 r;
  asm("v_cvt_pk_bf16_f32 %0, %1, %2" : "=v"(r) : "v"(a), "v"(b));
  return r;
}

// async global->LDS, 16B per lane; LDS dest = wave-uniform base + lane*16
__device__ __forceinline__ void gload16(const void* g, void* l) {
  __builtin_amdgcn_global_load_lds(
      (const __attribute__((address_space(1))) u32*)g,
      (__attribute__((address_space(3))) u32*)l, 16, 0, 0);
}

// ---------------- prep: cvt3 + bias_rearrange fused (grid-range split) ------
// blocks 0..2047  : fp32->bf16 convert of x|wqkv|wproj into contiguous ws
// blocks 2048..4095: bias rearrange (r17-proven bf16 body)
__global__ void prep(const float* __restrict__ x, const float* __restrict__ wqkv,
                     const float* __restrict__ wproj, u16* __restrict__ outc,
                     const float* __restrict__ ab, u16* __restrict__ biasr) {
  __shared__ u16 T[32][72];
  if (blockIdx.x < 2048) {
    int i = blockIdx.x * 256 + threadIdx.x;
    const int stride = 2048 * 256;
    for (; i < 3145728; i += stride) {        // float4 groups, 12.6M elems total
      const float* src = (i < 2097152) ? x + 4 * (long)i
                       : (i < 2883584) ? wqkv + 4 * ((long)i - 2097152)
                                       : wproj + 4 * ((long)i - 2883584);
      const float4 v = *(const float4*)src;
      ushort4 o;
      o.x = f2bf(v.x); o.y = f2bf(v.y); o.z = f2bf(v.z); o.w = f2bf(v.w);
      ((ushort4*)outc)[i] = o;
    }
  } else {
    const int blk  = blockIdx.x - 2048;   // 0..2047
    const int tid  = threadIdx.x;
    const int slot = blk >> 5;            // 0..63
    const int kt   = blk & 31;            // 0..31

    // phase 1: thread reads 8 contiguous floats of one q-row (coalesced)
    {
      const int qr = tid >> 3;            // 0..31
      const int fc = (tid & 7) * 8;       // 0..56
      const float* src = ab + (long)(slot * 32 + qr) * 2048 + kt * 64 + fc;
      const float4 a = *(const float4*)(src);
      const float4 b = *(const float4*)(src + 4);
      u16 t[8];
      t[0] = f2bf(a.x * LOG2E); t[1] = f2bf(a.y * LOG2E);
      t[2] = f2bf(a.z * LOG2E); t[3] = f2bf(a.w * LOG2E);
      t[4] = f2bf(b.x * LOG2E); t[5] = f2bf(b.y * LOG2E);
      t[6] = f2bf(b.z * LOG2E); t[7] = f2bf(b.w * LOG2E);
      *(s16x8*)&T[qr][fc] = *(s16x8*)t;
    }
    __syncthreads();

    // phase 2: gather fragment order from LDS, write contiguous 16B/thread
    {
      const int chunk = tid >> 6;         // 0..3
      const int lane  = tid & 63;
      const int q5    = lane & 31;
      const int hi    = lane >> 5;
      u16 o[8];
#pragma unroll
      for (int e = 0; e < 8; ++e) {
        const int vidx = chunk * 8 + e;
        const int kb = vidx >> 4, r = vidx & 15;
        const int key = kb * 32 + (r & 3) + 8 * (r >> 2) + 4 * hi;
        o[e] = T[q5][key];
      }
      *(s16x8*)(biasr + ((long)blk * 256 + tid) * 8) = *(s16x8*)o;
    }
  }
}

// ---------------- GEMM: C[M,N] = A[M,K] @ B[N,K]^T  (both bf16, row-major) ----
// 2-phase double-buffered staging (r17-proven): stage(next) overlaps
// compute(cur); one vmcnt(0)+barrier per K-tile.
// NOTE: 8-phase 256^2 (T3+T4) CONDEMNED here (r22: bank conflicts 1.4e7 +
// 1 block/CU -> 142us vs 68us; T2 swizzle prerequisite unavailable because
// pre-swizzled global_load_lds sources are condemned by r4/r5).
template<int EPI>
__global__ __launch_bounds__(256)
void gemm_bt(const u16* __restrict__ A, const u16* __restrict__ Bm,
             int M, int N, int K,
             const float* __restrict__ bias0, const float* __restrict__ bias1,
             u16* __restrict__ oq, u16* __restrict__ ok, u16* __restrict__ ov,
             float* __restrict__ outf)
{
  __shared__ u16 As[2][128 * 32];
  __shared__ u16 Bs[2][128 * 32];

  const int tid  = threadIdx.x;
  const int w    = tid >> 6;
  const int lane = tid & 63;
  const int lr   = lane & 15;
  const int lg   = lane >> 4;
  const int wr   = w >> 1, wc = w & 1;

  const int bm = blockIdx.y, bn = blockIdx.x;

  f32x4 acc[4][4];
#pragma unroll
  for (int i = 0; i < 4; ++i)
#pragma unroll
    for (int j = 0; j < 4; ++j) acc[i][j] = (f32x4){0.f, 0.f, 0.f, 0.f};

  const int rowA = bm * 128 + (tid >> 2);
  const int rowB = bn * 128 + (tid >> 2);
  const int colk = (tid & 3) * 8;

  const u16* ga0 = A  + (long)rowA * K + colk;
  const u16* gb0 = Bm + (long)rowB * K + colk;

  // prologue: stage tile 0
  gload16(ga0,          &As[0][w * 512]);
  gload16(ga0 + 64 * K, &As[0][2048 + w * 512]);
  gload16(gb0,          &Bs[0][w * 512]);
  gload16(gb0 + 64 * K, &Bs[0][2048 + w * 512]);
  asm volatile("s_waitcnt vmcnt(0)" ::: "memory");
  __syncthreads();

  const int NT = K >> 5;
  for (int t = 0; t < NT; ++t) {
    const int cur = t & 1;
    if (t + 1 < NT) {            // stage next tile into the other buffer
      const u16* ga = ga0 + (t + 1) * 32;
      const u16* gb = gb0 + (t + 1) * 32;
      gload16(ga,          &As[cur ^ 1][w * 512]);
      gload16(ga + 64 * K, &As[cur ^ 1][2048 + w * 512]);
      gload16(gb,          &Bs[cur ^ 1][w * 512]);
      gload16(gb + 64 * K, &Bs[cur ^ 1][2048 + w * 512]);
    }

    s16x8 af[4], bfr[4];
#pragma unroll
    for (int mi = 0; mi < 4; ++mi)
      af[mi] = *(const s16x8*)(&As[cur][(wr * 64 + mi * 16 + lr) * 32 + lg * 8]);
#pragma unroll
    for (int ni = 0; ni < 4; ++ni)
      bfr[ni] = *(const s16x8*)(&Bs[cur][(wc * 64 + ni * 16 + lr) * 32 + lg * 8]);
#pragma unroll
    for (int mi = 0; mi < 4; ++mi)
#pragma unroll
      for (int ni = 0; ni < 4; ++ni)
        acc[mi][ni] = mfma16(af[mi], bfr[ni], acc[mi][ni]);

    asm volatile("s_waitcnt vmcnt(0)" ::: "memory");   // next tile landed
    __syncthreads();                                    // all reads of cur done
  }

  const int gm0 = bm * 128 + wr * 64;
  const int gn0 = bn * 128 + wc * 64;

#pragma unroll
  for (int mi = 0; mi < 4; ++mi) {
#pragma unroll
    for (int ni = 0; ni < 4; ++ni) {
      const int col  = gn0 + ni * 16 + lr;
      const int row0 = gm0 + mi * 16 + lg * 4;
      if (EPI == 0) {
        const int which = col >> 10;          // 0=q 1=k 2=v
        const int cj    = col & 1023;
        const float badd = (which == 0) ? bias0[cj] : (which == 2 ? bias1[cj] : 0.f);
        const int h = cj >> 6, d = cj & 63;
#pragma unroll
        for (int r = 0; r < 4; ++r) {
          const int rowg = row0 + r;           // = b*2048 + l
          const int b = rowg >> 11, l = rowg & 2047;
          const int bh = b * 16 + h;
          float val = acc[mi][ni][r] + badd;
          if (which == 0) val *= QSC;          // fold softmax scale+log2e into q
          const u16 o = f2bf(val);
          if (which == 0)      oq[(bh * 2048 + l) * 64 + d] = o;
          else if (which == 1) ok[(bh * 2048 + l) * 64 + d] = o;
          else {
            // permute key bits 2<->3 so flash PV B-frags are lane-local
            const int lp = (l & ~12) | ((l & 4) << 1) | ((l & 8) >> 1);
            ov[(bh * 64 + d) * 2048 + lp] = o;
          }
        }
      } else {
        const float badd = bias0[col];
#pragma unroll
        for (int r = 0; r < 4; ++r)
          outf[(long)(row0 + r) * N + col] = acc[mi][ni][r] + badd;
      }
    }
  }
}

// ---------------- flash attention ----------------
// r15/r17 structure VERBATIM (passed, 107.5us, VGPR 88): 1024 blocks ->
// (bh, qt2) XCD-swizzled, 4 waves x 32-query fragments, coalesced reg-staged
// LDS K/V (padded rows), Os aliased onto Ks, fixed-max softmax, lane-local
// cvt_pk P-frags, key-permuted V, bf16 bias fragments.
// CONDEMNED (do not re-add): f32-bias scratch (r19/r20 absmax fails),
// s_setprio (r16: VGPR 88->128, -13%), __launch_bounds__ min-waves arg
// (r8/r9/r11 miscompiles), 8-phase GEMM schedule (r22).
__global__ __launch_bounds__(256)
void flash_attn(const u16* __restrict__ qbuf, const u16* __restrict__ kbuf,
                const u16* __restrict__ vtbuf, const u16* __restrict__ biasr,
                u16* __restrict__ oup)
{
  __shared__ u16 Ks[2][64 * 72];
  __shared__ u16 Vs[2][64 * 72];

  const int tid  = threadIdx.x;
  const int w    = tid >> 6;
  const int lane = tid & 63;
  const int lq   = lane & 31;
  const int hi   = lane >> 5;

  const int bid = blockIdx.x;
  const int swz = (bid & 7) * 128 + (bid >> 3);   // bijective, 1024 % 8 == 0
  const int bh  = swz >> 4, qt2 = swz & 15;
  const long base = (long)bh * (2048 * 64);

  // Q fragment (B-operand), one per wave
  const int qrow = qt2 * 128 + w * 32 + lq;
  s16x8 qf[4];
  {
    const u16* qp = qbuf + base + qrow * 64 + 8 * hi;
#pragma unroll
    for (int s = 0; s < 4; ++s) qf[s] = *(const s16x8*)(qp + 16 * s);
  }

  f32x16 oacc0, oacc1;
  float lacc[8];
#pragma unroll
  for (int r = 0; r < 16; ++r) { oacc0[r] = 0.f; oacc1[r] = 0.f; }
#pragma unroll
  for (int r = 0; r < 8; ++r) lacc[r] = 0.f;

  // bias slot = qrow>>5 = qt2*4 + w
  const u16* bslice = biasr + (long)(qt2 * 4 + w) * 65536 + lane * 8;

  // staging geometry: row sr in [0,32), chunk scc in [0,8)
  const int sr  = tid >> 3;
  const int scc = tid & 7;
  const u16* kg = kbuf  + base + sr * 64   + scc * 8;   // + kt*4096 ; +2048 = rows 32..63
  const u16* vg = vtbuf + base + sr * 2048 + scc * 8;   // + kt*64   ; +65536 = d 32..63
  const int wo0 = sr * 72 + scc * 8;
  const int wo1 = (32 + sr) * 72 + scc * 8;

  // prologue: stage tile 0
  {
    const s16x8 a0 = *(const s16x8*)(kg);
    const s16x8 a1 = *(const s16x8*)(kg + 2048);
    const s16x8 b0 = *(const s16x8*)(vg);
    const s16x8 b1 = *(const s16x8*)(vg + 65536);
    *(s16x8*)(&Ks[0][wo0]) = a0;  *(s16x8*)(&Ks[0][wo1]) = a1;
    *(s16x8*)(&Vs[0][wo0]) = b0;  *(s16x8*)(&Vs[0][wo1]) = b1;
  }
  __syncthreads();

  for (int kt = 0; kt < 32; ++kt) {
    const int cur = kt & 1;

    // issue next tile's global loads early (land under this iter's compute)
    s16x8 nk0, nk1, nv0, nv1;
    if (kt < 31) {
      const u16* kn = kg + (kt + 1) * 4096;
      const u16* vn = vg + (kt + 1) * 64;
      nk0 = *(const s16x8*)(kn);
      nk1 = *(const s16x8*)(kn + 2048);
      nv0 = *(const s16x8*)(vn);
      nv1 = *(const s16x8*)(vn + 65536);
    }

    // K/V fragments from LDS (padded rows; bank-balanced)
    s16x8 kf0[4], kf1[4], vf0[4], vf1[4];
    {
      const u16* kb0 = &Ks[cur][lq * 72];
      const u16* kb1 = &Ks[cur][(32 + lq) * 72];
      const u16* vb0 = &Vs[cur][lq * 72];
      const u16* vb1 = &Vs[cur][(32 + lq) * 72];
#pragma unroll
      for (int s = 0; s < 4; ++s) {
        const int off = (2 * s + hi) * 8;
        kf0[s] = *(const s16x8*)(kb0 + off);
        kf1[s] = *(const s16x8*)(kb1 + off);
        vf0[s] = *(const s16x8*)(vb0 + off);
        vf1[s] = *(const s16x8*)(vb1 + off);
      }
    }

    // bias fragments (coalesced dwordx4, bf16 pairs)
    u32x4 bb[4];
#pragma unroll
    for (int k = 0; k < 4; ++k)
      bb[k] = *(const u32x4*)(bslice + kt * 2048 + k * 512);

    // accumulator init from bias (1 VALU op per value)
    f32x16 sa0, sa1;
#pragma unroll
    for (int jw = 0; jw < 8; ++jw) {
      const u32 w0 = bb[jw >> 2][jw & 3];
      const u32 w1 = bb[2 + (jw >> 2)][jw & 3];
      sa0[2 * jw]     = __builtin_bit_cast(float, w0 << 16);
      sa0[2 * jw + 1] = __builtin_bit_cast(float, w0 & 0xFFFF0000u);
      sa1[2 * jw]     = __builtin_bit_cast(float, w1 << 16);
      sa1[2 * jw + 1] = __builtin_bit_cast(float, w1 & 0xFFFF0000u);
    }

    // S^T = K Q^T + bias  (log2 domain; q pre-scaled by QSC)
#pragma unroll
    for (int s = 0; s < 4; ++s) sa0 = mfma32(kf0[s], qf[s], sa0);
#pragma unroll
    for (int s = 0; s < 4; ++s) sa1 = mfma32(kf1[s], qf[s], sa1);

    // P = 2^s, no max subtraction; accumulate l partials
#pragma unroll
    for (int r = 0; r < 16; ++r) {
      sa0[r] = exp2_hw(sa0[r]);
      sa1[r] = exp2_hw(sa1[r]);
    }
#pragma unroll
    for (int r = 0; r < 8; ++r)
      lacc[r] += (sa0[r] + sa0[r + 8]) + (sa1[r] + sa1[r + 8]);

    // P fragments (lane-local by V key-permute)
    s16x8 pf[4];
#pragma unroll
    for (int ks = 0; ks < 4; ++ks) {
      const f32x16 ps = (ks & 2) ? sa1 : sa0;
      const int o = (ks & 1) * 8;
      u32x4 tt;
      tt[0] = cvtpk(ps[o + 0], ps[o + 1]);
      tt[1] = cvtpk(ps[o + 2], ps[o + 3]);
      tt[2] = cvtpk(ps[o + 4], ps[o + 5]);
      tt[3] = cvtpk(ps[o + 6], ps[o + 7]);
      pf[ks] = __builtin_bit_cast(s16x8, tt);
    }

    // O^T += V^T P^T
#pragma unroll
    for (int ks = 0; ks < 4; ++ks) {
      oacc0 = mfma32(vf0[ks], pf[ks], oacc0);
      oacc1 = mfma32(vf1[ks], pf[ks], oacc1);
    }

    // write next tile into the other buffer (its readers wait at the barrier)
    if (kt < 31) {
      *(s16x8*)(&Ks[cur ^ 1][wo0]) = nk0;
      *(s16x8*)(&Ks[cur ^ 1][wo1]) = nk1;
      *(s16x8*)(&Vs[cur ^ 1][wo0]) = nv0;
      *(s16x8*)(&Vs[cur ^ 1][wo1]) = nv1;
    }
    __syncthreads();
  }

  // epilogue: reduce l, normalize, transpose via LDS (aliased onto Ks — dead
  // after the final loop barrier), store [B, L, H*D] bf16
  u32 (*Os)[32][33] = (u32(*)[32][33])&Ks[0][0];
  const int b = bh >> 4, h = bh & 15;
  float l = ((lacc[0] + lacc[1]) + (lacc[2] + lacc[3]))
          + ((lacc[4] + lacc[5]) + (lacc[6] + lacc[7]));
  l += __shfl_xor(l, 32, 64);
  const float inv = 1.f / l;
#pragma unroll
  for (int i = 0; i < 8; ++i) {
    const int idx = (i & 1) + 2 * hi + 4 * (i >> 1);   // d0 = 2*idx
    Os[w][lq][idx]      = cvtpk(oacc0[2 * i] * inv, oacc0[2 * i + 1] * inv);
    Os[w][lq][idx + 16] = cvtpk(oacc1[2 * i] * inv, oacc1[2 * i + 1] * inv);
  }
  __syncthreads();
#pragma unroll
  for (int it = 0; it < 4; ++it) {
    const int q = it * 8 + (lane >> 3);
    const int c = (lane & 7) * 4;
    u32x4 v;
#pragma unroll
    for (int j = 0; j < 4; ++j) v[j] = Os[w][q][c + j];
    const long row = (long)(b * 2048 + qt2 * 128 + w * 32 + q);
    *(u32x4*)(oup + row * 1024 + h * 64 + (lane & 7) * 8) = v;
  }
}

extern "C" void kernel_launch(void* const* d_in, const int* in_sizes, int n_in,
                              void* d_out, int out_size, void* d_ws, size_t ws_size,
                              hipStream_t stream) {
  const float* x     = (const float*)d_in[0];
  const float* ab    = (const float*)d_in[1];
  const float* wqkv  = (const float*)d_in[2];
  const float* qbias = (const float*)d_in[3];
  const float* vbias = (const float*)d_in[4];
  const float* wproj = (const float*)d_in[5];
  const float* bproj = (const float*)d_in[6];
  float* out = (float*)d_out;

  // workspace layout (80 MB total) — r17-proven
  char* ws = (char*)d_ws;
  if (ws_size < 83886080u) return;  // refuse to corrupt memory
  u16* xb     = (u16*)(ws);              // 16 MB; reused as oup after QKV GEMM
  u16* wqkvb  = (u16*)(ws + 16777216);   // 6 MB (contiguous with xb)
  u16* wprojb = (u16*)(ws + 23068672);   // 2 MB (contiguous with wqkvb)
  u16* biasr  = (u16*)(ws + 25165824);   // 8 MB  (attn_bias, fragment order)
  u16* qbuf   = (u16*)(ws + 33554432);   // 16 MB  [B,H,L,D] (q pre-scaled)
  u16* kbuf   = (u16*)(ws + 50331648);   // 16 MB  [B,H,L,D]
  u16* vtbuf  = (u16*)(ws + 67108864);   // 16 MB  [B,H,D,L'] (key-permuted)

  prep<<<dim3(4096), dim3(256), 0, stream>>>(x, wqkv, wproj, xb, ab, biasr);

  gemm_bt<0><<<dim3(24, 64), dim3(256), 0, stream>>>(
      xb, wqkvb, 8192, 3072, 1024, qbias, vbias, qbuf, kbuf, vtbuf, nullptr);

  flash_attn<<<dim3(1024), dim3(256), 0, stream>>>(qbuf, kbuf, vtbuf, biasr, xb);

  gemm_bt<1><<<dim3(8, 64), dim3(256), 0, stream>>>(
      xb, wprojb, 8192, 1024, 1024, bproj, nullptr, nullptr, nullptr, nullptr, out);
}